// Round 8
// baseline (1128.608 us; speedup 1.0000x reference)
//
#include <hip/hip_runtime.h>
#include <hip/hip_cooperative_groups.h>
#include <hip/hip_bf16.h>
#include <hip/hip_fp16.h>
#include <math.h>

namespace cg = cooperative_groups;

#define N_NODES 50000
#define N_EDGES 800000
#define F_IN    11
#define HID     128
#define NC      16
#define NG      64
#define E_TOT   (N_EDGES + N_NODES)   // 850000 edges incl. self-loops
#define NBLK_POOL ((N_NODES + 255) / 256)  // 196
#define NEG_SLOPE 0.2f

#define NB   ((N_NODES + 63) >> 6)    // 782 buckets of 64 dst each
#define BCAP 4096                      // LDS pair-staging capacity in finalize
#define NHB  ((N_EDGES + 4095) / 4096) // hist chunks (196)
#define NSC  ((E_TOT + 4095) / 4096)   // scatter chunks (208)

typedef _Float16 half_t;
typedef __attribute__((ext_vector_type(2))) _Float16 half2v;
typedef __attribute__((ext_vector_type(4))) _Float16 half4;
typedef __attribute__((ext_vector_type(8))) _Float16 half8;
typedef __attribute__((ext_vector_type(4))) float f32x4;

__device__ __forceinline__ float leaky(float x) { return x >= 0.f ? x : NEG_SLOPE * x; }

// ================= shared device bodies (used by mega + fallback) =================

// layer-1 GEMM: wave per row, lane owns cols 2l,2l+1; fused alpha.
__device__ __forceinline__ void gemm1_body(const float* __restrict__ x,
                                           const float* __restrict__ W1,
                                           const float* __restrict__ a_s,
                                           const float* __restrict__ a_d,
                                           half_t* __restrict__ h16,
                                           float* __restrict__ asv, float* __restrict__ adv,
                                           int gwave, int nwaves, int lane) {
    int c0 = lane * 2, c1 = lane * 2 + 1;
    for (int row = gwave; row < N_NODES; row += nwaves) {
        const float* xr = x + (size_t)row * F_IN;
        float a0 = 0.f, a1 = 0.f;
#pragma unroll
        for (int k = 0; k < F_IN; ++k) {
            float xv = xr[k];
            a0 = fmaf(xv, W1[k * HID + c0], a0);
            a1 = fmaf(xv, W1[k * HID + c1], a1);
        }
        half2v hv; hv.x = (half_t)a0; hv.y = (half_t)a1;
        ((half2v*)(h16 + (size_t)row * HID))[lane] = hv;
        float ps = a0 * a_s[c0] + a1 * a_s[c1];
        float pd = a0 * a_d[c0] + a1 * a_d[c1];
#pragma unroll
        for (int m = 32; m; m >>= 1) { ps += __shfl_xor(ps, m); pd += __shfl_xor(pd, m); }
        if (lane == 0) { asv[row] = ps; adv[row] = pd; }
    }
}

// layer-2 GEMM: MFMA fp16, wave per 16 rows, no LDS, fused alpha.
__device__ __forceinline__ void gemm2_body(const half_t* __restrict__ A,
                                           const half_t* __restrict__ W2T,
                                           const float* __restrict__ a_s,
                                           const float* __restrict__ a_d,
                                           half_t* __restrict__ outp,
                                           float* __restrict__ asv, float* __restrict__ adv,
                                           int gwave, int nwaves, int lane) {
    int rl = lane & 15, kg = lane >> 4;
    for (int row0 = gwave * 16; row0 < N_NODES; row0 += nwaves * 16) {
        int arow = row0 + rl;
        if (arow >= N_NODES) arow = N_NODES - 1;  // clamp; masked on write
        const half8* Ap = (const half8*)(A + (size_t)arow * HID);
        half8 afrag[4];
#pragma unroll
        for (int kk = 0; kk < 4; ++kk) afrag[kk] = Ap[kk * 4 + kg];
        float ps[4] = {0.f, 0.f, 0.f, 0.f}, pd[4] = {0.f, 0.f, 0.f, 0.f};
#pragma unroll
        for (int ct = 0; ct < 8; ++ct) {
            f32x4 acc = {0.f, 0.f, 0.f, 0.f};
            const half8* Bp = (const half8*)(W2T + (size_t)(ct * 16 + rl) * HID);
#pragma unroll
            for (int kk = 0; kk < 4; ++kk)
                acc = __builtin_amdgcn_mfma_f32_16x16x32_f16(afrag[kk], Bp[kk * 4 + kg], acc, 0, 0, 0);
            int col = ct * 16 + rl;
            float as_c = a_s[col], ad_c = a_d[col];
#pragma unroll
            for (int i = 0; i < 4; ++i) {
                int r = row0 + kg * 4 + i;
                ps[i] = fmaf(acc[i], as_c, ps[i]);
                pd[i] = fmaf(acc[i], ad_c, pd[i]);
                if (r < N_NODES) outp[(size_t)r * HID + col] = (half_t)acc[i];
            }
        }
#pragma unroll
        for (int m = 1; m <= 8; m <<= 1) {
#pragma unroll
            for (int i = 0; i < 4; ++i) { ps[i] += __shfl_xor(ps[i], m); pd[i] += __shfl_xor(pd[i], m); }
        }
        if (rl == 0) {
#pragma unroll
            for (int i = 0; i < 4; ++i) {
                int r = row0 + kg * 4 + i;
                if (r < N_NODES) { asv[r] = ps[i]; adv[r] = pd[i]; }
            }
        }
    }
}

// fused segment-softmax + aggregation, C=128 fp16 rows. Wave per node.
__device__ __forceinline__ void agg128_body(const half_t* __restrict__ h16,
                                            const int* __restrict__ off,
                                            const int* __restrict__ csr,
                                            const float* __restrict__ asv,
                                            const float* __restrict__ adv,
                                            const float* __restrict__ bias,
                                            half_t* __restrict__ outp,
                                            int gwave, int nwaves, int lane) {
    int hw = lane >> 5;          // which edge of a pair this half-wave handles
    int qc = lane & 31;          // half4 index within the 128-ch fp16 row
    const half4* hp = (const half4*)h16;   // row = 32 half4
    for (int n = gwave; n < N_NODES; n += nwaves) {
        int o0 = off[n], o1 = off[n + 1];
        float ad_n = adv[n];
        float m = -INFINITY, den = 0.f;
        float4 acc = make_float4(0.f, 0.f, 0.f, 0.f);
        for (int base = o0; base < o1; base += 64) {
            int j = base + lane;
            bool valid = j < o1;
            int s = valid ? csr[j] : 0;
            float e = valid ? leaky(asv[s] + ad_n) : -INFINITY;
            float cm = e;
#pragma unroll
            for (int k = 32; k; k >>= 1) cm = fmaxf(cm, __shfl_xor(cm, k));
            float nm = fmaxf(m, cm);
            float rs = __expf(m - nm);  // m==-inf first batch -> 0, acc already 0
            den *= rs; acc.x *= rs; acc.y *= rs; acc.z *= rs; acc.w *= rs;
            float w = valid ? __expf(e - nm) : 0.f;
            float ws = w;
#pragma unroll
            for (int k = 32; k; k >>= 1) ws += __shfl_xor(ws, k);
            den += ws;
            m = nm;
            int cnt = min(64, o1 - base);
            int t = 0;
            for (; t + 16 <= cnt; t += 16) {  // 16 edges: 8 rows in flight per lane
                int sv[8]; float wv[8]; half4 vv[8];
#pragma unroll
                for (int u = 0; u < 8; ++u) {
                    sv[u] = __shfl(s, t + 2 * u + hw);
                    wv[u] = __shfl(w, t + 2 * u + hw);
                }
#pragma unroll
                for (int u = 0; u < 8; ++u) vv[u] = hp[(size_t)sv[u] * 32 + qc];
#pragma unroll
                for (int u = 0; u < 8; ++u) {
                    acc.x = fmaf(wv[u], (float)vv[u].x, acc.x);
                    acc.y = fmaf(wv[u], (float)vv[u].y, acc.y);
                    acc.z = fmaf(wv[u], (float)vv[u].z, acc.z);
                    acc.w = fmaf(wv[u], (float)vv[u].w, acc.w);
                }
            }
            for (; t + 8 <= cnt; t += 8) {
                int sv[4]; float wv[4]; half4 vv[4];
#pragma unroll
                for (int u = 0; u < 4; ++u) {
                    sv[u] = __shfl(s, t + 2 * u + hw);
                    wv[u] = __shfl(w, t + 2 * u + hw);
                }
#pragma unroll
                for (int u = 0; u < 4; ++u) vv[u] = hp[(size_t)sv[u] * 32 + qc];
#pragma unroll
                for (int u = 0; u < 4; ++u) {
                    acc.x = fmaf(wv[u], (float)vv[u].x, acc.x);
                    acc.y = fmaf(wv[u], (float)vv[u].y, acc.y);
                    acc.z = fmaf(wv[u], (float)vv[u].z, acc.z);
                    acc.w = fmaf(wv[u], (float)vv[u].w, acc.w);
                }
            }
            for (; t + 2 <= cnt; t += 2) {
                int s0 = __shfl(s, t + hw);
                float w0 = __shfl(w, t + hw);
                half4 v0 = hp[(size_t)s0 * 32 + qc];
                acc.x = fmaf(w0, (float)v0.x, acc.x); acc.y = fmaf(w0, (float)v0.y, acc.y);
                acc.z = fmaf(w0, (float)v0.z, acc.z); acc.w = fmaf(w0, (float)v0.w, acc.w);
            }
            if (t < cnt) {  // single trailing edge: half 0 only
                int s0 = __shfl(s, t);
                float w0 = __shfl(w, t);
                if (hw == 0) {
                    half4 v0 = hp[(size_t)s0 * 32 + qc];
                    acc.x = fmaf(w0, (float)v0.x, acc.x); acc.y = fmaf(w0, (float)v0.y, acc.y);
                    acc.z = fmaf(w0, (float)v0.z, acc.z); acc.w = fmaf(w0, (float)v0.w, acc.w);
                }
            }
        }
        acc.x += __shfl_xor(acc.x, 32); acc.y += __shfl_xor(acc.y, 32);
        acc.z += __shfl_xor(acc.z, 32); acc.w += __shfl_xor(acc.w, 32);
        if (hw == 0) {
            float inv = 1.f / den;  // deg >= 1 always (self-loop)
            float4 bv = ((const float4*)bias)[qc];
            half4 o;
            o.x = (half_t)fmaxf(fmaf(acc.x, inv, bv.x), 0.f);
            o.y = (half_t)fmaxf(fmaf(acc.y, inv, bv.y), 0.f);
            o.z = (half_t)fmaxf(fmaf(acc.z, inv, bv.z), 0.f);
            o.w = (half_t)fmaxf(fmaf(acc.w, inv, bv.w), 0.f);
            ((half4*)outp)[(size_t)n * 32 + qc] = o;
        }
    }
}

// C=16 aggregation: 8 lane-groups x 8 lanes; fp16 rows, f32 out. Wave per node.
__device__ __forceinline__ void agg16_body(const half_t* __restrict__ h,
                                           const int* __restrict__ off,
                                           const int* __restrict__ csr,
                                           const float* __restrict__ asv,
                                           const float* __restrict__ adv,
                                           const float* __restrict__ bias,
                                           float* __restrict__ outp,
                                           int gwave, int nwaves, int lane) {
    int g = lane >> 3, pr = lane & 7;
    const half2v* hp = (const half2v*)h;   // row = 8 half2v (32B)
    for (int n = gwave; n < N_NODES; n += nwaves) {
        int o0 = off[n], o1 = off[n + 1];
        float ad_n = adv[n];
        float m = -INFINITY, den = 0.f;
        float ax = 0.f, ay = 0.f;
        for (int base = o0; base < o1; base += 64) {
            int j = base + lane;
            bool valid = j < o1;
            int s = valid ? csr[j] : 0;
            float e = valid ? leaky(asv[s] + ad_n) : -INFINITY;
            float cm = e;
#pragma unroll
            for (int k = 32; k; k >>= 1) cm = fmaxf(cm, __shfl_xor(cm, k));
            float nm = fmaxf(m, cm);
            float rs = __expf(m - nm);
            den *= rs; ax *= rs; ay *= rs;
            float w = valid ? __expf(e - nm) : 0.f;
            float ws = w;
#pragma unroll
            for (int k = 32; k; k >>= 1) ws += __shfl_xor(ws, k);
            den += ws;
            m = nm;
            int cnt = min(64, o1 - base);
            for (int t = g; t < cnt; t += 8) {
                int st = __shfl(s, t);
                float wt = __shfl(w, t);
                half2v v = hp[(size_t)st * 8 + pr];
                ax = fmaf(wt, (float)v.x, ax); ay = fmaf(wt, (float)v.y, ay);
            }
        }
        ax += __shfl_xor(ax, 8);  ay += __shfl_xor(ay, 8);
        ax += __shfl_xor(ax, 16); ay += __shfl_xor(ay, 16);
        ax += __shfl_xor(ax, 32); ay += __shfl_xor(ay, 32);
        if (g == 0) {
            float inv = 1.f / den;
            float vx = fmaxf(fmaf(ax, inv, bias[pr * 2]), 0.f);
            float vy = fmaxf(fmaf(ay, inv, bias[pr * 2 + 1]), 0.f);
            ((float2*)outp)[(size_t)n * 8 + pr] = make_float2(vx, vy);
        }
    }
}

// mean-pool finalize + sigmoid: one output per participating thread slot.
__device__ __forceinline__ void pool_final_body(const float* __restrict__ part,
                                                float* __restrict__ outp,
                                                int gid, int gstride) {
    for (int o = gid; o < NG * NC; o += gstride) {
        int g = o >> 4, c = o & 15;
        float sum = 0.f, cntv = 0.f;
        for (int b = 0; b < NBLK_POOL; ++b) {
            sum  += part[(size_t)b * (NG * 17) + g * 17 + c];
            cntv += part[(size_t)b * (NG * 17) + g * 17 + 16];
        }
        float v = sum / fmaxf(cntv, 1.f);
        outp[o] = 1.f / (1.f + __expf(-v));
    }
}

// ================= cooperative mega-kernel (13 phases, 1 dispatch) =================

struct MegaArgs {
    const float* x; const int* ei; const int* bat;
    const float* W1; const float* as1; const float* ad1; const float* b1;
    const float* W2; const float* as2; const float* ad2; const float* b2;
    const float* W3; const float* as3; const float* ad3; const float* b3;
    float* outp;
    int* off; int* csr; int* gcount; int* bOff; int* gcur; unsigned* pairs;
    half_t* h16; half_t* o16; half_t* W2T; half_t* h3; float* o3;
    float* asv; float* adv; float* part;
};

union SharedU {
    int hist_cnt[NB];
    struct { int cnt[NB]; int base[NB]; } scat;
    struct { unsigned lp[BCAP]; int deg[64]; int offs[65]; int cnt[64]; } fin;
    int scan_ls[256];
    float hs[16][HID + 1];
    float sp[NG * 17];
};

__global__ __launch_bounds__(256, 4) void gat_mega_kernel(MegaArgs P) {
    cg::grid_group grid = cg::this_grid();
    const int tid = threadIdx.x;
    const int bid = blockIdx.x;
    const int G = gridDim.x;
    const int gthread = bid * 256 + tid;
    const int nthreads = G * 256;
    const int wid = tid >> 6, lane = tid & 63;
    const int gwave = bid * 4 + wid, nwaves = G * 4;
    __shared__ SharedU u;

    // -- phase 0: zero bucket counts --
    for (int i = gthread; i < NB; i += nthreads) P.gcount[i] = 0;
    grid.sync();

    // -- phase 1: bucket histogram (+ W2 -> fp16 W2T transpose on spare blocks) --
    for (int c = bid; c < NHB + 64; c += G) {
        if (c < NHB) {
            for (int i = tid; i < NB; i += 256) u.hist_cnt[i] = 0;
            __syncthreads();
            int e0 = c * 4096 + tid;
#pragma unroll
            for (int k = 0; k < 16; ++k) {
                int e = e0 + k * 256;
                if (e < N_EDGES) atomicAdd(&u.hist_cnt[P.ei[N_EDGES + e] >> 6], 1);
            }
            __syncthreads();
            for (int i = tid; i < NB; i += 256)
                if (u.hist_cnt[i]) atomicAdd(&P.gcount[i], u.hist_cnt[i]);
            __syncthreads();
        } else {
            int id = (c - NHB) * 256 + tid;   // id = col*128 + k
            if (id < HID * HID) {
                int col = id >> 7, k = id & 127;
                P.W2T[id] = (half_t)P.W2[k * HID + col];
            }
        }
    }
    grid.sync();

    // -- phase 2: exclusive scan over buckets (+ analytic self-loops); block 0 --
    if (bid == 0) {
        int base = tid * 4;
        int v0 = 0, v1 = 0, v2 = 0, v3 = 0;
        if (base + 0 < NB) v0 = P.gcount[base + 0] + min(64, N_NODES - ((base + 0) << 6));
        if (base + 1 < NB) v1 = P.gcount[base + 1] + min(64, N_NODES - ((base + 1) << 6));
        if (base + 2 < NB) v2 = P.gcount[base + 2] + min(64, N_NODES - ((base + 2) << 6));
        if (base + 3 < NB) v3 = P.gcount[base + 3] + min(64, N_NODES - ((base + 3) << 6));
        int pre1 = v0, pre2 = v0 + v1, pre3 = v0 + v1 + v2;
        u.scan_ls[tid] = pre3 + v3;
        __syncthreads();
        for (int ofs = 1; ofs < 256; ofs <<= 1) {
            int xv = (tid >= ofs) ? u.scan_ls[tid - ofs] : 0;
            __syncthreads();
            u.scan_ls[tid] += xv;
            __syncthreads();
        }
        int excl = (tid > 0) ? u.scan_ls[tid - 1] : 0;
        if (base + 0 < NB) { P.bOff[base + 0] = excl;        P.gcur[base + 0] = excl; }
        if (base + 1 < NB) { P.bOff[base + 1] = excl + pre1; P.gcur[base + 1] = excl + pre1; }
        if (base + 2 < NB) { P.bOff[base + 2] = excl + pre2; P.gcur[base + 2] = excl + pre2; }
        if (base + 3 < NB) { P.bOff[base + 3] = excl + pre3; P.gcur[base + 3] = excl + pre3; }
        if (tid == 0) P.bOff[NB] = E_TOT;
    }
    grid.sync();

    // -- phase 3: bucketed scatter of packed (src | dst&63) --
    for (int c = bid; c < NSC; c += G) {
        for (int i = tid; i < NB; i += 256) u.scat.cnt[i] = 0;
        __syncthreads();
        int s[16], d[16];
        int e0 = c * 4096 + tid;
#pragma unroll
        for (int k = 0; k < 16; ++k) {
            int e = e0 + k * 256;
            if (e < N_EDGES) { s[k] = P.ei[e]; d[k] = P.ei[N_EDGES + e]; }
            else if (e < E_TOT) { s[k] = d[k] = e - N_EDGES; }   // self-loop
            else d[k] = -1;
            if (d[k] >= 0) atomicAdd(&u.scat.cnt[d[k] >> 6], 1);
        }
        __syncthreads();
        for (int i = tid; i < NB; i += 256)
            u.scat.base[i] = u.scat.cnt[i] ? atomicAdd(&P.gcur[i], u.scat.cnt[i]) : 0;
        __syncthreads();
        for (int i = tid; i < NB; i += 256) u.scat.cnt[i] = 0;
        __syncthreads();
#pragma unroll
        for (int k = 0; k < 16; ++k) {
            if (d[k] >= 0) {
                int b = d[k] >> 6;
                int r = atomicAdd(&u.scat.cnt[b], 1);
                P.pairs[u.scat.base[b] + r] = (unsigned)s[k] | ((unsigned)(d[k] & 63) << 16);
            }
        }
        __syncthreads();
    }
    grid.sync();

    // -- phase 4: per-bucket CSR finalize --
    if (bid == 0 && tid == 0) P.off[N_NODES] = E_TOT;
    for (int b = bid; b < NB; b += G) {
        int d0 = b << 6;
        int nd = N_NODES - d0; nd = nd > 64 ? 64 : nd;
        int lo = P.bOff[b], hi = P.bOff[b + 1], n = hi - lo;
        if (tid < 64) { u.fin.deg[tid] = 0; u.fin.cnt[tid] = 0; }
        __syncthreads();
        bool staged = (n <= BCAP);
        for (int i = tid; i < n; i += 256) {
            unsigned pp = P.pairs[lo + i];
            if (staged) u.fin.lp[i] = pp;
            atomicAdd(&u.fin.deg[pp >> 16], 1);
        }
        __syncthreads();
        if (tid == 0) {
            int a = 0;
#pragma unroll
            for (int i = 0; i < 64; ++i) { u.fin.offs[i] = a; a += u.fin.deg[i]; }
            u.fin.offs[64] = a;
        }
        __syncthreads();
        if (tid < nd) P.off[d0 + tid] = lo + u.fin.offs[tid];
        for (int i = tid; i < n; i += 256) {
            unsigned pp = staged ? u.fin.lp[i] : P.pairs[lo + i];
            int ld = pp >> 16;
            int r = atomicAdd(&u.fin.cnt[ld], 1);
            P.csr[lo + u.fin.offs[ld] + r] = (int)(pp & 0xFFFF);
        }
        __syncthreads();
    }
    grid.sync();

    // -- phase 5: layer-1 GEMM + alpha --
    gemm1_body(P.x, P.W1, P.as1, P.ad1, P.h16, P.asv, P.adv, gwave, nwaves, lane);
    grid.sync();

    // -- phase 6: layer-1 aggregation --
    agg128_body(P.h16, P.off, P.csr, P.asv, P.adv, P.b1, P.o16, gwave, nwaves, lane);
    grid.sync();

    // -- phase 7: layer-2 MFMA GEMM + alpha --
    gemm2_body(P.o16, P.W2T, P.as2, P.ad2, P.h16, P.asv, P.adv, gwave, nwaves, lane);
    grid.sync();

    // -- phase 8: layer-2 aggregation --
    agg128_body(P.h16, P.off, P.csr, P.asv, P.adv, P.b2, P.o16, gwave, nwaves, lane);
    grid.sync();

    // -- phase 9: layer-3 GEMM (LDS-staged) + alpha --
    {
        const int NG3 = (N_NODES + 15) / 16;
        int col = tid & 15, r = tid >> 4;
        for (int blk = bid; blk < NG3; blk += G) {
            int row0 = blk * 16;
            for (int i = tid; i < 16 * HID; i += 256) {
                int rr = i >> 7, cc = i & 127;
                int gr = row0 + rr;
                u.hs[rr][cc] = (gr < N_NODES) ? (float)P.o16[(size_t)gr * HID + cc] : 0.f;
            }
            __syncthreads();
            float acc = 0.f;
#pragma unroll 4
            for (int k = 0; k < HID; ++k) acc = fmaf(u.hs[r][k], P.W3[k * NC + col], acc);
            int gr = row0 + r;
            float ps = acc * P.as3[col], pd = acc * P.ad3[col];
#pragma unroll
            for (int m = 1; m <= 8; m <<= 1) { ps += __shfl_xor(ps, m); pd += __shfl_xor(pd, m); }
            if (gr < N_NODES) {
                P.h3[(size_t)gr * NC + col] = (half_t)acc;
                if (col == 0) { P.asv[gr] = ps; P.adv[gr] = pd; }
            }
            __syncthreads();
        }
    }
    grid.sync();

    // -- phase 10: layer-3 aggregation --
    agg16_body(P.h3, P.off, P.csr, P.asv, P.adv, P.b3, P.o3, gwave, nwaves, lane);
    grid.sync();

    // -- phase 11: pool partials --
    for (int blk = bid; blk < NBLK_POOL; blk += G) {
        for (int i = tid; i < NG * 17; i += 256) u.sp[i] = 0.f;
        __syncthreads();
        int n = blk * 256 + tid;
        if (n < N_NODES) {
            int g = P.bat[n];
            const float4* hv = (const float4*)(P.o3 + (size_t)n * NC);
#pragma unroll
            for (int j = 0; j < 4; ++j) {
                float4 v = hv[j];
                atomicAdd(&u.sp[g * 17 + j * 4 + 0], v.x);
                atomicAdd(&u.sp[g * 17 + j * 4 + 1], v.y);
                atomicAdd(&u.sp[g * 17 + j * 4 + 2], v.z);
                atomicAdd(&u.sp[g * 17 + j * 4 + 3], v.w);
            }
            atomicAdd(&u.sp[g * 17 + 16], 1.f);
        }
        __syncthreads();
        for (int i = tid; i < NG * 17; i += 256) P.part[(size_t)blk * (NG * 17) + i] = u.sp[i];
        __syncthreads();
    }
    grid.sync();

    // -- phase 12: pool finalize + sigmoid --
    pool_final_body(P.part, P.outp, gthread, nthreads);
}

// ================= fallback kernels (round-7 proven path) =================

__global__ __launch_bounds__(256) void fb_hist_w2t_kernel(const int* __restrict__ ei,
                                                          int* __restrict__ gcount,
                                                          const float* __restrict__ W2,
                                                          half_t* __restrict__ W2T) {
    int tid = threadIdx.x;
    if (blockIdx.x >= NHB) {
        int id = (blockIdx.x - NHB) * 256 + tid;
        if (id < HID * HID) {
            int col = id >> 7, k = id & 127;
            W2T[id] = (half_t)W2[k * HID + col];
        }
        return;
    }
    __shared__ int cnt[NB];
    for (int i = tid; i < NB; i += 256) cnt[i] = 0;
    __syncthreads();
    int e0 = blockIdx.x * 4096 + tid;
#pragma unroll
    for (int k = 0; k < 16; ++k) {
        int e = e0 + k * 256;
        if (e < N_EDGES) atomicAdd(&cnt[ei[N_EDGES + e] >> 6], 1);
    }
    __syncthreads();
    for (int i = tid; i < NB; i += 256)
        if (cnt[i]) atomicAdd(&gcount[i], cnt[i]);
}

__global__ void fb_scanB_kernel(const int* __restrict__ gcount, int* __restrict__ bOff,
                                int* __restrict__ gcur) {
    __shared__ int ls[1024];
    int tid = threadIdx.x;
    int v = 0;
    if (tid < NB) {
        int sl = N_NODES - (tid << 6);
        sl = sl > 64 ? 64 : sl;
        v = gcount[tid] + sl;
    }
    ls[tid] = v;
    __syncthreads();
    for (int ofs = 1; ofs < 1024; ofs <<= 1) {
        int x = (tid >= ofs) ? ls[tid - ofs] : 0;
        __syncthreads();
        ls[tid] += x;
        __syncthreads();
    }
    int excl = (tid > 0) ? ls[tid - 1] : 0;
    if (tid < NB) { bOff[tid] = excl; gcur[tid] = excl; }
    if (tid == 0) bOff[NB] = E_TOT;
}

__global__ __launch_bounds__(256) void fb_scatter_kernel(const int* __restrict__ ei,
                                                         int* __restrict__ gcur,
                                                         unsigned* __restrict__ pairs) {
    __shared__ int cnt[NB];
    __shared__ int base[NB];
    int tid = threadIdx.x;
    for (int i = tid; i < NB; i += 256) cnt[i] = 0;
    __syncthreads();
    int s[16], d[16];
    int e0 = blockIdx.x * 4096 + tid;
#pragma unroll
    for (int k = 0; k < 16; ++k) {
        int e = e0 + k * 256;
        if (e < N_EDGES) { s[k] = ei[e]; d[k] = ei[N_EDGES + e]; }
        else if (e < E_TOT) { s[k] = d[k] = e - N_EDGES; }
        else d[k] = -1;
        if (d[k] >= 0) atomicAdd(&cnt[d[k] >> 6], 1);
    }
    __syncthreads();
    for (int i = tid; i < NB; i += 256)
        base[i] = cnt[i] ? atomicAdd(&gcur[i], cnt[i]) : 0;
    __syncthreads();
    for (int i = tid; i < NB; i += 256) cnt[i] = 0;
    __syncthreads();
#pragma unroll
    for (int k = 0; k < 16; ++k) {
        if (d[k] >= 0) {
            int b = d[k] >> 6;
            int r = atomicAdd(&cnt[b], 1);
            pairs[base[b] + r] = (unsigned)s[k] | ((unsigned)(d[k] & 63) << 16);
        }
    }
}

__global__ __launch_bounds__(256) void fb_finalize_kernel(const unsigned* __restrict__ pairs,
                                                          const int* __restrict__ bOff,
                                                          int* __restrict__ off,
                                                          int* __restrict__ csr) {
    __shared__ unsigned lp[BCAP];
    __shared__ int deg[64], offs[65], cnt[64];
    int b = blockIdx.x, tid = threadIdx.x;
    int d0 = b << 6;
    int nd = N_NODES - d0; nd = nd > 64 ? 64 : nd;
    int lo = bOff[b], hi = bOff[b + 1], n = hi - lo;
    if (tid < 64) { deg[tid] = 0; cnt[tid] = 0; }
    __syncthreads();
    bool staged = (n <= BCAP);
    for (int i = tid; i < n; i += 256) {
        unsigned p = pairs[lo + i];
        if (staged) lp[i] = p;
        atomicAdd(&deg[p >> 16], 1);
    }
    __syncthreads();
    if (tid == 0) {
        int a = 0;
#pragma unroll
        for (int i = 0; i < 64; ++i) { offs[i] = a; a += deg[i]; }
        offs[64] = a;
    }
    __syncthreads();
    if (tid < nd) off[d0 + tid] = lo + offs[tid];
    if (b == (int)gridDim.x - 1 && tid == 0) off[N_NODES] = E_TOT;
    for (int i = tid; i < n; i += 256) {
        unsigned p = staged ? lp[i] : pairs[lo + i];
        int ld = p >> 16;
        int r = atomicAdd(&cnt[ld], 1);
        csr[lo + offs[ld] + r] = (int)(p & 0xFFFF);
    }
}

__global__ __launch_bounds__(256) void fb_gemm1_kernel(const float* x, const float* W1,
                                                       const float* a_s, const float* a_d,
                                                       half_t* h16, float* asv, float* adv) {
    int lane = threadIdx.x & 63;
    int gwave = (blockIdx.x * blockDim.x + threadIdx.x) >> 6;
    int nwaves = (gridDim.x * blockDim.x) >> 6;
    gemm1_body(x, W1, a_s, a_d, h16, asv, adv, gwave, nwaves, lane);
}

__global__ __launch_bounds__(256) void fb_gemm2_kernel(const half_t* A, const half_t* W2T,
                                                       const float* a_s, const float* a_d,
                                                       half_t* outp, float* asv, float* adv) {
    int lane = threadIdx.x & 63;
    int gwave = (blockIdx.x * blockDim.x + threadIdx.x) >> 6;
    int nwaves = (gridDim.x * blockDim.x) >> 6;
    gemm2_body(A, W2T, a_s, a_d, outp, asv, adv, gwave, nwaves, lane);
}

__global__ __launch_bounds__(256) void fb_gemm3_kernel(const half_t* A16, const float* W,
                                                       const float* a_s, const float* a_d,
                                                       half_t* outp, float* asv, float* adv) {
    __shared__ float hs[16][HID + 1];
    int tid = threadIdx.x;
    int row0 = blockIdx.x * 16;
    for (int i = tid; i < 16 * HID; i += 256) {
        int r = i >> 7, c = i & 127;
        int gr = row0 + r;
        hs[r][c] = (gr < N_NODES) ? (float)A16[(size_t)gr * HID + c] : 0.f;
    }
    __syncthreads();
    int col = tid & 15, r = tid >> 4;
    float acc = 0.f;
#pragma unroll 4
    for (int k = 0; k < HID; ++k) acc = fmaf(hs[r][k], W[k * NC + col], acc);
    int gr = row0 + r;
    float ps = acc * a_s[col], pd = acc * a_d[col];
#pragma unroll
    for (int m = 1; m <= 8; m <<= 1) { ps += __shfl_xor(ps, m); pd += __shfl_xor(pd, m); }
    if (gr < N_NODES) {
        outp[(size_t)gr * NC + col] = (half_t)acc;
        if (col == 0) { asv[gr] = ps; adv[gr] = pd; }
    }
}

__global__ __launch_bounds__(256) void fb_agg128_kernel(const half_t* h16, const int* off,
                                                        const int* csr, const float* asv,
                                                        const float* adv, const float* bias,
                                                        half_t* outp) {
    int lane = threadIdx.x & 63;
    int gwave = (blockIdx.x * blockDim.x + threadIdx.x) >> 6;
    int nwaves = (gridDim.x * blockDim.x) >> 6;
    agg128_body(h16, off, csr, asv, adv, bias, outp, gwave, nwaves, lane);
}

__global__ __launch_bounds__(256) void fb_agg16_kernel(const half_t* h, const int* off,
                                                       const int* csr, const float* asv,
                                                       const float* adv, const float* bias,
                                                       float* outp) {
    int lane = threadIdx.x & 63;
    int gwave = (blockIdx.x * blockDim.x + threadIdx.x) >> 6;
    int nwaves = (gridDim.x * blockDim.x) >> 6;
    agg16_body(h, off, csr, asv, adv, bias, outp, gwave, nwaves, lane);
}

__global__ void fb_pool_partial_kernel(const float* __restrict__ h3, const int* __restrict__ batch,
                                       float* __restrict__ part) {
    __shared__ float sp[NG * 17];
    int tid = threadIdx.x;
    for (int i = tid; i < NG * 17; i += 256) sp[i] = 0.f;
    __syncthreads();
    int n = blockIdx.x * 256 + tid;
    if (n < N_NODES) {
        int g = batch[n];
        const float4* hv = (const float4*)(h3 + (size_t)n * NC);
#pragma unroll
        for (int j = 0; j < 4; ++j) {
            float4 v = hv[j];
            atomicAdd(&sp[g * 17 + j * 4 + 0], v.x);
            atomicAdd(&sp[g * 17 + j * 4 + 1], v.y);
            atomicAdd(&sp[g * 17 + j * 4 + 2], v.z);
            atomicAdd(&sp[g * 17 + j * 4 + 3], v.w);
        }
        atomicAdd(&sp[g * 17 + 16], 1.f);
    }
    __syncthreads();
    for (int i = tid; i < NG * 17; i += 256) part[(size_t)blockIdx.x * (NG * 17) + i] = sp[i];
}

__global__ void fb_pool_final_kernel(const float* __restrict__ part, float* __restrict__ outp) {
    pool_final_body(part, outp, blockIdx.x * 256 + threadIdx.x, gridDim.x * 256);
}

// ================= launch =================

extern "C" void kernel_launch(void* const* d_in, const int* in_sizes, int n_in,
                              void* d_out, int out_size, void* d_ws, size_t ws_size,
                              hipStream_t stream) {
    const float* x   = (const float*)d_in[0];
    const int*   ei  = (const int*)d_in[1];
    // d_in[2] edge_attr: unused by reference
    const int*   bat = (const int*)d_in[3];
    const float* W1  = (const float*)d_in[4];
    const float* as1 = (const float*)d_in[5];
    const float* ad1 = (const float*)d_in[6];
    const float* b1  = (const float*)d_in[7];
    const float* W2  = (const float*)d_in[8];
    const float* as2 = (const float*)d_in[9];
    const float* ad2 = (const float*)d_in[10];
    const float* b2  = (const float*)d_in[11];
    const float* W3  = (const float*)d_in[12];
    const float* as3 = (const float*)d_in[13];
    const float* ad3 = (const float*)d_in[14];
    const float* b3  = (const float*)d_in[15];
    float* outp = (float*)d_out;

    char* p = (char*)d_ws;
    auto carve = [&](size_t bytes) {
        char* r = p;
        p += (bytes + 255) & ~(size_t)255;
        return r;
    };
    int*      off    = (int*)carve((size_t)(N_NODES + 1) * 4);
    int*      csr    = (int*)carve((size_t)E_TOT * 4);
    int*      gcount = (int*)carve((size_t)NB * 4);
    int*      bOff   = (int*)carve((size_t)(NB + 1) * 4);
    int*      gcur   = (int*)carve((size_t)NB * 4);
    unsigned* pairs  = (unsigned*)carve((size_t)E_TOT * 4);
    half_t*   h16    = (half_t*)carve((size_t)N_NODES * HID * 2);
    half_t*   o16    = (half_t*)carve((size_t)N_NODES * HID * 2);
    half_t*   W2T    = (half_t*)carve((size_t)HID * HID * 2);
    half_t*   h3     = (half_t*)carve((size_t)N_NODES * NC * 2);
    float*    o3     = (float*)carve((size_t)N_NODES * NC * 4);
    float*    asv    = (float*)carve((size_t)N_NODES * 4);
    float*    adv    = (float*)carve((size_t)N_NODES * 4);
    float*    part   = (float*)carve((size_t)NBLK_POOL * NG * 17 * 4);

    MegaArgs prm;
    prm.x = x; prm.ei = ei; prm.bat = bat;
    prm.W1 = W1; prm.as1 = as1; prm.ad1 = ad1; prm.b1 = b1;
    prm.W2 = W2; prm.as2 = as2; prm.ad2 = ad2; prm.b2 = b2;
    prm.W3 = W3; prm.as3 = as3; prm.ad3 = ad3; prm.b3 = b3;
    prm.outp = outp;
    prm.off = off; prm.csr = csr; prm.gcount = gcount; prm.bOff = bOff;
    prm.gcur = gcur; prm.pairs = pairs;
    prm.h16 = h16; prm.o16 = o16; prm.W2T = W2T; prm.h3 = h3; prm.o3 = o3;
    prm.asv = asv; prm.adv = adv; prm.part = part;

    int perCU = 0;
    hipError_t oe = hipOccupancyMaxActiveBlocksPerMultiprocessor(
        &perCU, (const void*)gat_mega_kernel, 256, 0);
    if (oe != hipSuccess || perCU < 1) { (void)hipGetLastError(); perCU = 2; }
    int G = perCU * 256;           // 256 CUs on MI355X
    if (G > 2048) G = 2048;

    void* args[] = { &prm };
    hipError_t err = hipLaunchCooperativeKernel((const void*)gat_mega_kernel,
                                                dim3(G), dim3(256), args, 0, stream);
    if (err != hipSuccess) {
        (void)hipGetLastError();   // clear sticky error; use proven multi-kernel path
        hipMemsetAsync(gcount, 0, (size_t)NB * 4, stream);
        fb_hist_w2t_kernel<<<NHB + 64, 256, 0, stream>>>(ei, gcount, W2, W2T);
        fb_scanB_kernel<<<1, 1024, 0, stream>>>(gcount, bOff, gcur);
        fb_scatter_kernel<<<NSC, 256, 0, stream>>>(ei, gcur, pairs);
        fb_finalize_kernel<<<NB, 256, 0, stream>>>(pairs, bOff, off, csr);
        fb_gemm1_kernel<<<(N_NODES + 3) / 4, 256, 0, stream>>>(x, W1, as1, ad1, h16, asv, adv);
        fb_agg128_kernel<<<(N_NODES + 3) / 4, 256, 0, stream>>>(h16, off, csr, asv, adv, b1, o16);
        fb_gemm2_kernel<<<(N_NODES / 64 + 3) / 4, 256, 0, stream>>>(o16, W2T, as2, ad2, h16, asv, adv);
        fb_agg128_kernel<<<(N_NODES + 3) / 4, 256, 0, stream>>>(h16, off, csr, asv, adv, b2, o16);
        fb_gemm3_kernel<<<(N_NODES + 15) / 16, 256, 0, stream>>>(o16, W3, as3, ad3, h3, asv, adv);
        fb_agg16_kernel<<<(N_NODES + 3) / 4, 256, 0, stream>>>(h3, off, csr, asv, adv, b3, o3);
        fb_pool_partial_kernel<<<NBLK_POOL, 256, 0, stream>>>(o3, bat, part);
        fb_pool_final_kernel<<<4, 256, 0, stream>>>(part, outp);
    }
}